// Round 4
// baseline (547.192 us; speedup 1.0000x reference)
//
#include <hip/hip_runtime.h>
#include <cstdint>

#define S_DIM 128
#define L_DIM 512
#define INimD 256
#define OUTF  128

typedef __bf16 bf16x8 __attribute__((ext_vector_type(8)));
typedef float  f32x16 __attribute__((ext_vector_type(16)));

__device__ __forceinline__ unsigned short f2bf(float f) {
  unsigned int u = __float_as_uint(f);
  u = (u + 0x7fffu + ((u >> 16) & 1u)) >> 16;
  return (unsigned short)u;
}

// l_f fragment-major layout: index ((d*16 + s8*2 + half)*512 + i)*8 + t
//   where s = s8*16 + half*8 + t  (d: 0..31, i: node 0..511)
// Writer: k_lnproj. Reader: k_pair phase-A a-frags (coalesced 16B/lane).

// ---------------- kernel 1: LayerNorm + projection ---------------------------
// act[s,l,j] = (LN(x[s,l,:]) . w[j,:] + b[j]) * mask[s,l]
// l -> l_f (fragment-major, d<32); r -> r_t[(l*32+e)*128 + s] (e = d-32)
__global__ __launch_bounds__(256) void k_lnproj(
    const float* __restrict__ x, const float* __restrict__ mask,
    const float* __restrict__ w, const float* __restrict__ b,
    unsigned short* __restrict__ l_f, unsigned short* __restrict__ r_t)
{
  __shared__ float xh[16][260];              // 16 rows of xhat (fp32)
  __shared__ float part[4][16][64];          // quarter-K partial sums
  __shared__ unsigned short act_s[64][136];  // [j][s] bf16 staging
  const int tid = threadIdx.x;
  const int wv = tid >> 6, lane = tid & 63;
  const int l = blockIdx.x;

  // w quarter in registers: thread = (j=lane, k in [wv*64, wv*64+64))
  float wreg[64];
  {
    const float4* wp = (const float4*)(w + (size_t)lane * INimD + wv * 64);
#pragma unroll
    for (int q = 0; q < 16; ++q) ((float4*)wreg)[q] = wp[q];
  }

  for (int pass = 0; pass < 8; ++pass) {
    // ---- LN: row handled by 16 lanes; this thread covers float4 idx sub+16q
    const int row = tid >> 4;              // 0..15
    const int s   = pass * 16 + row;
    const int sub = tid & 15;
    const float4* xr = (const float4*)(x + ((size_t)s * L_DIM + l) * INimD);
    float4 v[4];
#pragma unroll
    for (int q = 0; q < 4; ++q) v[q] = xr[sub + 16 * q];
    float sm = 0.f, sq = 0.f;
#pragma unroll
    for (int q = 0; q < 4; ++q) {
      sm += v[q].x + v[q].y + v[q].z + v[q].w;
      sq += v[q].x*v[q].x + v[q].y*v[q].y + v[q].z*v[q].z + v[q].w*v[q].w;
    }
#pragma unroll
    for (int off = 8; off > 0; off >>= 1) {
      sm += __shfl_xor(sm, off);
      sq += __shfl_xor(sq, off);
    }
    const float mu  = sm * (1.0f / 256.0f);
    const float var = sq * (1.0f / 256.0f) - mu * mu;
    const float rs  = rsqrtf(var + 1e-5f);
#pragma unroll
    for (int q = 0; q < 4; ++q) {
      float4 h;
      h.x = (v[q].x - mu) * rs; h.y = (v[q].y - mu) * rs;
      h.z = (v[q].z - mu) * rs; h.w = (v[q].w - mu) * rs;
      ((float4*)&xh[row][0])[sub + 16 * q] = h;
    }
    __syncthreads();

    // ---- matvec: wave wv = k-quarter, lane = j; 16 rows accumulated
    float acc[16];
#pragma unroll
    for (int r = 0; r < 16; ++r) acc[r] = 0.f;
    const float* xbase = &xh[0][0] + wv * 64;
#pragma unroll 4
    for (int kk = 0; kk < 16; ++kk) {
      const float4 wv4 = ((const float4*)wreg)[kk];
#pragma unroll
      for (int r = 0; r < 16; ++r) {
        const float4 xq = *(const float4*)(xbase + r * 260 + kk * 4); // broadcast
        acc[r] += wv4.x*xq.x + wv4.y*xq.y + wv4.z*xq.z + wv4.w*xq.w;
      }
    }
#pragma unroll
    for (int r = 0; r < 16; ++r) part[wv][r][lane] = acc[r];
    __syncthreads();

    // ---- reduce 4 quarters: thread = (row=tid>>4, 4 j's)
    {
      const int rrow = tid >> 4;
      const float m = mask[(size_t)(pass * 16 + rrow) * L_DIM + l];
#pragma unroll
      for (int u = 0; u < 4; ++u) {
        const int j = (tid & 15) * 4 + u;
        float sum = part[0][rrow][j] + part[1][rrow][j]
                  + part[2][rrow][j] + part[3][rrow][j] + b[j];
        act_s[j][pass * 16 + rrow] = f2bf(sum * m);
      }
    }
    // no sync needed here: next pass's first sync orders part reads vs writes
  }
  __syncthreads();

  // ---- write-out: 4 threads per d-row, 32 s-elements each
  const int d = tid >> 2, c = (tid & 3) * 32;   // d 0..63, c in {0,32,64,96}
  uint4 outv[4];
  unsigned short* p = (unsigned short*)outv;
#pragma unroll
  for (int q = 0; q < 32; ++q) p[q] = act_s[d][c + q];
  if (d < 32) {
    // fragment-major: chunk ch covers s = c+ch*8 .. +7
    const int q0 = tid & 3;
#pragma unroll
    for (int ch = 0; ch < 4; ++ch) {
      const int s8 = q0 * 2 + (ch >> 1), half = ch & 1;
      unsigned short* dst = l_f + (((size_t)(d * 16 + s8 * 2 + half)) * 512 + l) * 8;
      *(uint4*)dst = outv[ch];
    }
  } else {
    unsigned short* dst = r_t + ((size_t)l * 32 + (d - 32)) * S_DIM + c;
    ((uint4*)dst)[0] = outv[0];
    ((uint4*)dst)[1] = outv[1];
    ((uint4*)dst)[2] = outv[2];
    ((uint4*)dst)[3] = outv[3];
  }
}

// ---------------- kernel 2: recip[i,j] = 1 / (mask^T mask + 0.001) -----------
__global__ __launch_bounds__(256) void k_norm(const float* __restrict__ mask,
                                              float* __restrict__ recip)
{
  const int i = blockIdx.y * 16 + (threadIdx.x >> 4);
  const int j = blockIdx.x * 16 + (threadIdx.x & 15);
  float acc = 0.f;
  for (int s = 0; s < S_DIM; ++s)
    acc += mask[(size_t)s * L_DIM + i] * mask[(size_t)s * L_DIM + j];
  recip[(size_t)i * L_DIM + j] = 1.0f / (acc + 0.001f);
}

// ---------------- kernel 3: W2 -> bf16 in B-fragment order -------------------
// WB[((kt*4 + ft)*64 + lane)*8 + jj] = W[k = kt*16 + (lane>>5)*8 + jj][f = ft*32 + (lane&31)]
__global__ __launch_bounds__(256) void k_wb(const float* __restrict__ W,
                                            unsigned short* __restrict__ WB)
{
  const int gid = blockIdx.x * 256 + threadIdx.x;   // 0..16383
  const int ln = gid & 63;
  const int ftkt = gid >> 6;
  const int ft = ftkt & 3, kt = ftkt >> 2;
  const int f  = ft * 32 + (ln & 31);
  const int kb = kt * 16 + (ln >> 5) * 8;
#pragma unroll
  for (int jj = 0; jj < 8; ++jj) {
    const int k = kb + jj;
    WB[(size_t)gid * 8 + jj] = f2bf(W[(size_t)k * OUTF + f]);
  }
}

// ---------------- kernel 4: fused pair-GEMM (LDS-lean, dbuf, 1 barrier/iter) -
// Block: 16 i x 4 j = 64 pairs. Per K-chunk c (2 d's x 32 e):
//  A: wave wv -> jl=wv: G[32 rows=(dc,ii)][32 e] via MFMA (K=s=128, r in regs)
//  g -> g_lds[c&1] (bf16). One __syncthreads.
//  B: wave wv -> pairs [(wv>>1)*32,+32), f-half (wv&1): 2 n-tiles, K=64 chunk
__global__ __launch_bounds__(256, 3) void k_pair(
    const unsigned short* __restrict__ l_f, const unsigned short* __restrict__ r_t,
    const unsigned short* __restrict__ WB, const float* __restrict__ recip,
    const float* __restrict__ bias, float* __restrict__ out)
{
  __shared__ __align__(16) unsigned short g_lds[2][64][80];  // 20.5 KB
  const int tid = threadIdx.x;
  const int wv = tid >> 6, lane = tid & 63;
  const int half = lane >> 5, ln = lane & 31;
  const int j0 = blockIdx.x * 4, i0 = blockIdx.y * 16;

  // r-fragments (c-invariant) in registers: lane holds r[(j0+wv)*32+ln][s-slice]
  bf16x8 rb[8];
#pragma unroll
  for (int s8 = 0; s8 < 8; ++s8)
    rb[s8] = *(const bf16x8*)(r_t + ((size_t)((j0 + wv) * 32 + ln)) * S_DIM
                              + s8 * 16 + half * 8);

  f32x16 acc0, acc1;
#pragma unroll
  for (int q = 0; q < 16; ++q) { acc0[q] = 0.f; acc1[q] = 0.f; }

  for (int c = 0; c < 16; ++c) {
    const int gbuf = c & 1;
    // ---- phase A: a-frags direct from l_f (coalesced fragment-major)
    bf16x8 af[8];
#pragma unroll
    for (int s8 = 0; s8 < 8; ++s8)
      af[s8] = *(const bf16x8*)(l_f
          + (((size_t)((2 * c + (ln >> 4)) * 16 + s8 * 2 + half)) * 512
             + (i0 + (ln & 15))) * 8);
    f32x16 g;
#pragma unroll
    for (int q = 0; q < 16; ++q) g[q] = 0.f;
#pragma unroll
    for (int s8 = 0; s8 < 8; ++s8)
      g = __builtin_amdgcn_mfma_f32_32x32x16_bf16(af[s8], rb[s8], g, 0, 0, 0);

    // C-layout -> g_lds[gbuf][pair][kl]
#pragma unroll
    for (int reg = 0; reg < 16; ++reg) {
      const int r  = (reg & 3) + 8 * (reg >> 2) + 4 * half;  // dc*16 + ii
      const int p  = (r & 15) * 4 + wv;                      // ii*4 + jl
      const int kl = (r >> 4) * 32 + ln;                     // dc*32 + e
      g_lds[gbuf][p][kl] = f2bf(g[reg]);
    }
    __syncthreads();

    // ---- phase B: wave -> (pair-half = wv>>1, f-half = wv&1)
    const int prow = (wv >> 1) * 32;
#pragma unroll
    for (int kt = 0; kt < 4; ++kt) {
      const int gkt = c * 4 + kt;
      bf16x8 a = *(const bf16x8*)&g_lds[gbuf][prow + ln][kt * 16 + half * 8];
      bf16x8 bw0 = *(const bf16x8*)(WB + ((size_t)(gkt * 4 + (wv & 1) * 2 + 0) * 64 + lane) * 8);
      bf16x8 bw1 = *(const bf16x8*)(WB + ((size_t)(gkt * 4 + (wv & 1) * 2 + 1) * 64 + lane) * 8);
      acc0 = __builtin_amdgcn_mfma_f32_32x32x16_bf16(a, bw0, acc0, 0, 0, 0);
      acc1 = __builtin_amdgcn_mfma_f32_32x32x16_bf16(a, bw1, acc1, 0, 0, 0);
    }
    // no second barrier: next iter writes g_lds[1-gbuf] (double buffer)
  }

  // epilogue: rows = pairs prow + r, cols f = (wv&1)*64 + at*32 + ln
  const int pbase = (wv >> 1) * 32, fbase = (wv & 1) * 64;
#pragma unroll
  for (int at = 0; at < 2; ++at) {
    const f32x16 a = at ? acc1 : acc0;
    const int f = fbase + at * 32 + ln;
    const float bi = bias[f];
#pragma unroll
    for (int reg = 0; reg < 16; ++reg) {
      const int r = (reg & 3) + 8 * (reg >> 2) + 4 * half;
      const int p = pbase + r;
      const int i = i0 + (p >> 2), j = j0 + (p & 3);
      const float val = (a[reg] + bi) * recip[(size_t)i * L_DIM + j];
      out[((size_t)i * L_DIM + j) * OUTF + f] = val;
    }
  }
}

extern "C" void kernel_launch(void* const* d_in, const int* in_sizes, int n_in,
                              void* d_out, int out_size, void* d_ws, size_t ws_size,
                              hipStream_t stream) {
  const float* x    = (const float*)d_in[0];   // node_repr (128,512,256)
  const float* mask = (const float*)d_in[1];   // (128,512)
  const float* w    = (const float*)d_in[2];   // w_proj (64,256)
  const float* b    = (const float*)d_in[3];   // b_proj (64)
  const float* W    = (const float*)d_in[4];   // out_weights (32,32,128)
  const float* bias = (const float*)d_in[5];   // out_bias (128)
  float* out = (float*)d_out;

  char* ws = (char*)d_ws;
  unsigned short* l_f = (unsigned short*)ws;                         // 4 MB
  unsigned short* r_t = (unsigned short*)(ws + (4u << 20));          // 4 MB
  unsigned short* WB  = (unsigned short*)(ws + (8u << 20));          // 256 KB
  float* recip = (float*)(ws + (8u << 20) + (512u << 10));           // 1 MB

  hipLaunchKernelGGL(k_lnproj, dim3(512),      dim3(256), 0, stream, x, mask, w, b, l_f, r_t);
  hipLaunchKernelGGL(k_norm,   dim3(32, 32),   dim3(256), 0, stream, mask, recip);
  hipLaunchKernelGGL(k_wb,     dim3(64),       dim3(256), 0, stream, W, WB);
  hipLaunchKernelGGL(k_pair,   dim3(128, 32),  dim3(256), 0, stream, l_f, r_t, WB, recip, bias, out);
}